// Round 7
// baseline (157.236 us; speedup 1.0000x reference)
//
#include <hip/hip_runtime.h>
#include <math.h>

#define NSITES 131072      // 32*16*16*16
#define HALFS  (NSITES / 2)
#define PL     (NSITES * 9)   // floats per feature plane

struct cplx { float re, im; };

__device__ __forceinline__ cplx cadd(cplx a, cplx b) { return {a.re + b.re, a.im + b.im}; }
__device__ __forceinline__ cplx cmul(cplx a, cplx b) {
    return { fmaf(a.re, b.re, -(a.im * b.im)), fmaf(a.re, b.im, a.im * b.re) };
}

// 12-byte vector load (global_load_dwordx3); rows are 36 B so only 4B-aligned
struct __attribute__((aligned(4))) f3 { float x, y, z; };
__device__ __forceinline__ f3 ld3(const float* __restrict__ p) { return *(const f3*)p; }
__device__ __forceinline__ void ld9(const float* __restrict__ p, float* r) {
    f3 a = *(const f3*)p, b = *(const f3*)(p + 3), c = *(const f3*)(p + 6);
    r[0] = a.x; r[1] = a.y; r[2] = a.z;
    r[3] = b.x; r[4] = b.y; r[5] = b.z;
    r[6] = c.x; r[7] = c.y; r[8] = c.z;
}

// 4-lane-group broadcast: lane i reads from lane (i & 0x1C) | g.
// BitMode ds_swizzle imm = (xor<<10)|(or<<5)|and, and=0x1C, or=g, xor=0.
// Accumulate the 9 pre-reduced E inputs broadcast from group-lane g.
template<int IMM>
__device__ __forceinline__ void accf(const float* a, float wf, float* acc) {
    #pragma unroll
    for (int m = 0; m < 9; m++)
        acc[m] = fmaf(wf,
            __int_as_float(__builtin_amdgcn_ds_swizzle(__float_as_int(a[m]), IMM)),
            acc[m]);
}

// owner pre-reduction: the 9 floats E consumes from one feature.
// re(W-W^dag) antisymmetric -> 3 diffs; im symmetric -> 3 pair-sums + 3 diag.
__device__ __forceinline__ void prered(f3 q, f3 s, const float* wi, float* fr) {
    fr[0] = q.x - q.z;     fr[1] = q.y - s.y;     fr[2] = s.x - s.z;
    fr[3] = wi[1] + wi[3]; fr[4] = wi[2] + wi[6]; fr[5] = wi[5] + wi[7];
    fr[6] = wi[0];         fr[7] = wi[4];         fr[8] = wi[8];
}

// 8-DOF anti-hermitian traceless E:
//  E = [[i*ed0, er01+i*ei01, er02+i*ei02],
//       [-er01+i*ei01, i*ed1, er12+i*ei12],
//       [-er02+i*ei02, -er12+i*ei12, i*ed2]]
struct Edof { float er01, er02, er12, ei01, ei02, ei12, ed0, ed1, ed2; };

__device__ __forceinline__ Edof make_edof(const float* acc) {
    Edof E;
    E.er01 = acc[0]; E.er02 = acc[1]; E.er12 = acc[2];
    E.ei01 = acc[3]; E.ei02 = acc[4]; E.ei12 = acc[5];
    float t3 = (acc[6] + acc[7] + acc[8]) * (2.f / 3.f);
    E.ed0 = fmaf(2.f, acc[6], -t3);
    E.ed1 = fmaf(2.f, acc[7], -t3);
    E.ed2 = fmaf(2.f, acc[8], -t3);     // == -ed0-ed1
    return E;
}

// exp(E) = g0 I + g1 E + g2 E^2 via Cayley-Hamilton (p real, q imaginary),
// scaling from exponent bits of ||E||_F^2, Taylor(10) + repeated squaring.
__device__ __forceinline__ void expm_coeffs(const Edof& E, cplx& g0o, cplx& g1o, cplx& g2o)
{
    float r2 = fmaf(E.er01, E.er01, fmaf(E.er02, E.er02, fmaf(E.er12, E.er12,
               fmaf(E.ei01, E.ei01, fmaf(E.ei02, E.ei02, E.ei12 * E.ei12)))));
    r2 = fmaf(2.f, r2, fmaf(E.ed0, E.ed0, fmaf(E.ed1, E.ed1, E.ed2 * E.ed2)));

    const float n01 = fmaf(E.ei01, E.ei01, E.er01 * E.er01);
    const float n02 = fmaf(E.ei02, E.ei02, E.er02 * E.er02);
    const float n12 = fmaf(E.ei12, E.ei12, E.er12 * E.er12);
    const float zre = fmaf(E.ei01, E.ei12, -(E.er01 * E.er12));
    const float zim = -fmaf(E.ei01, E.er12, E.er01 * E.ei12);
    const float detH = E.ed0 * E.ed1 * E.ed2
                     + 2.f * fmaf(zre, E.ei02, -(zim * E.er02))
                     - fmaf(E.ed0, n12, fmaf(E.ed1, n02, E.ed2 * n01));

    int e; (void)frexpf(r2, &e);                 // r2 = m*2^e, m in [0.5,1)
    int sc = (e <= -2) ? 0 : min(1 + ((e + 1) >> 1), 40);
    const float inv  = __int_as_float((127 - sc) << 23);   // 2^-sc
    const float inv2 = inv * inv;
    const float px   = -0.5f * r2 * inv2;        // p of scaled X (real)
    const float qxi  = -detH * (inv2 * inv);     // q of scaled X = i*qxi

    cplx T0 = {1.f, 0.f}, T1 = {0.f, 0.f}, T2 = {0.f, 0.f};
    cplx S0 = {1.f, 0.f}, S1 = {0.f, 0.f}, S2 = {0.f, 0.f};
    #pragma unroll
    for (int n = 1; n <= 10; n++) {
        float c  = 1.f / (float)n;               // folds to a literal
        float qc = qxi * c;
        cplx nT0 = { -qc * T2.im, qc * T2.re };
        cplx nT1 = { c * fmaf(px, T2.re, T0.re), c * fmaf(px, T2.im, T0.im) };
        cplx nT2 = { c * T1.re, c * T1.im };
        T0 = nT0; T1 = nT1; T2 = nT2;
        S0 = cadd(S0, T0); S1 = cadd(S1, T1); S2 = cadd(S2, T2);
    }

    const float q2 = 2.f * qxi;
    for (int k = 0; k < sc; k++) {
        cplx f0 = S0, f1 = S1, f2 = S2;
        cplx f12 = cmul(f1, f2);
        cplx f01 = cmul(f0, f1);
        cplx f02 = cmul(f0, f2);
        float f00re = fmaf(f0.re, f0.re, -(f0.im * f0.im)), f00im = 2.f * f0.re * f0.im;
        float f11re = fmaf(f1.re, f1.re, -(f1.im * f1.im)), f11im = 2.f * f1.re * f1.im;
        float f22re = fmaf(f2.re, f2.re, -(f2.im * f2.im)), f22im = 2.f * f2.re * f2.im;
        S0.re = fmaf(-q2, f12.im, f00re);
        S0.im = fmaf( q2, f12.re, f00im);
        S1.re = fmaf(-qxi, f22im, 2.f * fmaf(px, f12.re, f01.re));
        S1.im = fmaf( qxi, f22re, 2.f * fmaf(px, f12.im, f01.im));
        S2.re = fmaf(px, f22re, fmaf(2.f, f02.re, f11re));
        S2.im = fmaf(px, f22im, fmaf(2.f, f02.im, f11im));
    }
    g0o = S0;
    g1o = { S1.re * inv,  S1.im * inv  };
    g2o = { S2.re * inv2, S2.im * inv2 };
}

__device__ __forceinline__ void ecol(const Edof& E, cplx m0, cplx m1, cplx m2,
                                     cplx& v0, cplx& v1, cplx& v2)
{
    v0.re = fmaf(-E.ed0, m0.im, fmaf(E.er01, m1.re, fmaf(-E.ei01, m1.im, fmaf(E.er02, m2.re, -(E.ei02 * m2.im)))));
    v0.im = fmaf( E.ed0, m0.re, fmaf(E.er01, m1.im, fmaf( E.ei01, m1.re, fmaf(E.er02, m2.im,  (E.ei02 * m2.re)))));
    v1.re = fmaf(-E.er01, m0.re, fmaf(-E.ei01, m0.im, fmaf(-E.ed1, m1.im, fmaf(E.er12, m2.re, -(E.ei12 * m2.im)))));
    v1.im = fmaf(-E.er01, m0.im, fmaf( E.ei01, m0.re, fmaf( E.ed1, m1.re, fmaf(E.er12, m2.im,  (E.ei12 * m2.re)))));
    v2.re = fmaf(-E.er02, m0.re, fmaf(-E.ei02, m0.im, fmaf(-E.er12, m1.re, fmaf(-E.ei12, m1.im, -(E.ed2 * m2.im)))));
    v2.im = fmaf(-E.er02, m0.im, fmaf( E.ei02, m0.re, fmaf(-E.er12, m1.im, fmaf( E.ei12, m1.re,  (E.ed2 * m2.re)))));
}

__device__ __forceinline__ float ocomb(cplx g0, cplx g1, cplx g2, cplx m, cplx v, cplx z) {
    return fmaf(g0.re, m.re, fmaf(-g0.im, m.im, fmaf(g1.re, v.re, fmaf(-g1.im, v.im,
           fmaf(g2.re, z.re, -(g2.im * z.im))))));
}

__device__ __forceinline__ void apply_store(const Edof& E, cplx g0, cplx g1, cplx g2,
                                            const float* ur, const float* ui,
                                            float* __restrict__ ob)
{
    float o[9];
    #pragma unroll
    for (int b = 0; b < 3; b++) {
        cplx m0 = { ur[b],     ui[b]     };
        cplx m1 = { ur[3 + b], ui[3 + b] };
        cplx m2 = { ur[6 + b], ui[6 + b] };
        cplx v0, v1, v2, z0, z1, z2;
        ecol(E, m0, m1, m2, v0, v1, v2);   // V col = E * U col
        ecol(E, v0, v1, v2, z0, z1, z2);   // Z col = E * V col
        o[b]     = ocomb(g0, g1, g2, m0, v0, z0);
        o[3 + b] = ocomb(g0, g1, g2, m1, v1, z1);
        o[6 + b] = ocomb(g0, g1, g2, m2, v2, z2);
    }
    *(f3*)(ob)     = { o[0], o[1], o[2] };
    *(f3*)(ob + 3) = { o[3], o[4], o[5] };
    *(f3*)(ob + 6) = { o[6], o[7], o[8] };
}

// TWO (site, mu) ITEMS PER LANE. Empirical law from R0-R5: per-wave lifetime
// ~13-15 us is INVARIANT under memory structure (1 DMA burst / 51 loads / 21
// loads all identical), and duration = (waves of work / ~11 concurrent) x
// lifetime. So halve the wave count: each lane handles sites s and s+65536
// (both coalesced), one 20-load W window feeds both items, each item's U load
// flies under its own expm. If lifetime stays ~15-18 us, duration ~halves.
//
// launch_bounds NOTE (measured): (256,8) 64-VGPR cap -> 155 MB spill;
// (256,6) pressure mode -> 48.7 MB spill; (256,4) clean (R0/R3/R4/R5).
__global__ __launch_bounds__(256, 4) void lge_exp_kernel(
    const float* __restrict__ U_re, const float* __restrict__ U_im,
    const float* __restrict__ W_re, const float* __restrict__ W_im,
    const float* __restrict__ ahw,  float* __restrict__ out)
{
    const int gid = blockIdx.x * 256 + threadIdx.x;   // 0..262143
    const int sA  = gid >> 2;          // item-A site (4-lane group shares it)
    const int mu  = gid & 3;
    const int sB  = sA + HALFS;        // item-B site, same coalescing pattern

    // ahw row for this mu: two aligned float4 loads
    const float4* ahw4 = (const float4*)ahw;
    float4 wlo = ahw4[mu * 2], whi = ahw4[mu * 2 + 1];
    const float wfv[8] = { wlo.x, wlo.y, wlo.z, wlo.w, whi.x, whi.y, whi.z, whi.w };

    // this lane cooperatively owns features mu and mu+4 for its group's sites
    const float* WrLo = W_re + (size_t)mu * PL;
    const float* WiLo = W_im + (size_t)mu * PL;
    const float* WrHi = W_re + (size_t)(mu + 4) * PL;
    const float* WiHi = W_im + (size_t)(mu + 4) * PL;
    const size_t bA = (size_t)sA * 9, bB = (size_t)sB * 9;

    // ---- ONE load window: 20 loads for both items' W ----
    f3 qAl = ld3(WrLo + bA + 1), sAl = ld3(WrLo + bA + 5);
    f3 qAh = ld3(WrHi + bA + 1), sAh = ld3(WrHi + bA + 5);
    f3 qBl = ld3(WrLo + bB + 1), sBl = ld3(WrLo + bB + 5);
    f3 qBh = ld3(WrHi + bB + 1), sBh = ld3(WrHi + bB + 5);
    float iAl[9]; ld9(WiLo + bA, iAl);
    float iAh[9]; ld9(WiHi + bA, iAh);
    float iBl[9]; ld9(WiLo + bB, iBl);
    float iBh[9]; ld9(WiHi + bB, iBh);

    // ---- owner pre-reduction (consumes raw W as it arrives) ----
    float faA[9], fbA[9], faB[9], fbB[9];
    prered(qAl, sAl, iAl, faA);
    prered(qAh, sAh, iAh, fbA);
    prered(qBl, sBl, iBl, faB);
    prered(qBh, sBh, iBh, fbB);

    // ---- E accumulation via 4-lane-group broadcasts, both items ----
    // acc layout: {er01, er02, er12, si01, si02, si12, d0, d4, d8}
    float accA[9] = {0.f,0.f,0.f,0.f,0.f,0.f,0.f,0.f,0.f};
    float accB[9] = {0.f,0.f,0.f,0.f,0.f,0.f,0.f,0.f,0.f};
    accf<0x1C>(faA, wfv[0], accA); accf<0x3C>(faA, wfv[1], accA);
    accf<0x5C>(faA, wfv[2], accA); accf<0x7C>(faA, wfv[3], accA);
    accf<0x1C>(fbA, wfv[4], accA); accf<0x3C>(fbA, wfv[5], accA);
    accf<0x5C>(fbA, wfv[6], accA); accf<0x7C>(fbA, wfv[7], accA);
    accf<0x1C>(faB, wfv[0], accB); accf<0x3C>(faB, wfv[1], accB);
    accf<0x5C>(faB, wfv[2], accB); accf<0x7C>(faB, wfv[3], accB);
    accf<0x1C>(fbB, wfv[4], accB); accf<0x3C>(fbB, wfv[5], accB);
    accf<0x5C>(fbB, wfv[6], accB); accf<0x7C>(fbB, wfv[7], accB);

    const Edof EA = make_edof(accA);
    const Edof EB = make_edof(accB);

    // ---- item A: U in flight under expm, then apply+store ----
    const size_t ubA = ((size_t)mu * NSITES + sA) * 9;
    float urA[9], uiA[9];
    ld9(U_re + ubA, urA); ld9(U_im + ubA, uiA);
    cplx g0A, g1A, g2A;
    expm_coeffs(EA, g0A, g1A, g2A);
    apply_store(EA, g0A, g1A, g2A, urA, uiA, out + ubA);

    // ---- item B ----
    const size_t ubB = ((size_t)mu * NSITES + sB) * 9;
    float urB[9], uiB[9];
    ld9(U_re + ubB, urB); ld9(U_im + ubB, uiB);
    cplx g0B, g1B, g2B;
    expm_coeffs(EB, g0B, g1B, g2B);
    apply_store(EB, g0B, g1B, g2B, urB, uiB, out + ubB);
}

extern "C" void kernel_launch(void* const* d_in, const int* in_sizes, int n_in,
                              void* d_out, int out_size, void* d_ws, size_t ws_size,
                              hipStream_t stream) {
    const float* U_re = (const float*)d_in[0];
    const float* U_im = (const float*)d_in[1];
    const float* W_re = (const float*)d_in[2];
    const float* W_im = (const float*)d_in[3];
    const float* ahw  = (const float*)d_in[4];
    float* out = (float*)d_out;
    // two (site, mu) items per lane: 262144 lanes = 1024 blocks x 256
    lge_exp_kernel<<<dim3(NSITES * 4 / 2 / 256), dim3(256), 0, stream>>>(
        U_re, U_im, W_re, W_im, ahw, out);
}

// Round 8
// 147.530 us; speedup vs baseline: 1.0658x; 1.0658x over previous
//
#include <hip/hip_runtime.h>
#include <math.h>

#define NSITES 131072      // 32*16*16*16

struct cplx { float re, im; };

__device__ __forceinline__ cplx cadd(cplx a, cplx b) { return {a.re + b.re, a.im + b.im}; }
__device__ __forceinline__ cplx cmul(cplx a, cplx b) {
    return { fmaf(a.re, b.re, -(a.im * b.im)), fmaf(a.re, b.im, a.im * b.re) };
}

// 12-byte vector load (global_load_dwordx3); rows are 36 B so only 4B-aligned
struct __attribute__((aligned(4))) f3 { float x, y, z; };
__device__ __forceinline__ f3 ld3(const float* __restrict__ p) { return *(const f3*)p; }
__device__ __forceinline__ void ld9(const float* __restrict__ p, float* r) {
    f3 a = *(const f3*)p, b = *(const f3*)(p + 3), c = *(const f3*)(p + 6);
    r[0] = a.x; r[1] = a.y; r[2] = a.z;
    r[3] = b.x; r[4] = b.y; r[5] = b.z;
    r[6] = c.x; r[7] = c.y; r[8] = c.z;
}

// V = E*M column product using the 8-DOF anti-hermitian E:
//  E = [[i*ed0, er01+i*ei01, er02+i*ei02],
//       [-er01+i*ei01, i*ed1, er12+i*ei12],
//       [-er02+i*ei02, -er12+i*ei12, i*ed2]]
#define ECOL(m0, m1, m2, v0, v1, v2) do { \
    v0.re = fmaf(-ed0, m0.im, fmaf(er01, m1.re, fmaf(-ei01, m1.im, fmaf(er02, m2.re, -(ei02 * m2.im))))); \
    v0.im = fmaf( ed0, m0.re, fmaf(er01, m1.im, fmaf( ei01, m1.re, fmaf(er02, m2.im,  (ei02 * m2.re))))); \
    v1.re = fmaf(-er01, m0.re, fmaf(-ei01, m0.im, fmaf(-ed1, m1.im, fmaf(er12, m2.re, -(ei12 * m2.im))))); \
    v1.im = fmaf(-er01, m0.im, fmaf( ei01, m0.re, fmaf( ed1, m1.re, fmaf(er12, m2.im,  (ei12 * m2.re))))); \
    v2.re = fmaf(-er02, m0.re, fmaf(-ei02, m0.im, fmaf(-er12, m1.re, fmaf(-ei12, m1.im, -(ed2 * m2.im))))); \
    v2.im = fmaf(-er02, m0.im, fmaf( ei02, m0.re, fmaf(-er12, m1.im, fmaf( ei12, m1.re,  (ed2 * m2.re))))); \
} while (0)

// real part of g0*m + g1*v + g2*z
#define OCOMB(m, v, z) \
    fmaf(g0.re, m.re, fmaf(-g0.im, m.im, fmaf(g1.re, v.re, fmaf(-g1.im, v.im, \
    fmaf(g2.re, z.re, -(g2.im * z.im))))))

// MAKESPAN MODEL (fits R0-R7): duration = N_wg * r + L, with workgroup
// dispatch rate r ~ 13 ns/WG and per-wave lifetime L ~ 15 us. Four different
// memory structures all measured ~42-45 us because the 2048-WG dispatch tail
// (~27 us) dominated and is structure-invariant (occupancy never >40% -- CUs
// starved for WGs, not resources). THIS ROUND: identical per-lane code to R4
// (proven: VGPR 44, zero scratch), but 1024-thread blocks x 512 WGs instead
// of 256 x 2048. Same 8192 waves, same coalescing; dispatch tail -20 us.
//
// launch_bounds NOTE (measured): 2nd arg is min waves/EU. (256,8) 64-VGPR cap
// -> 155 MB spill; (256,6) pressure mode -> 48.7 MB spill; 4 waves/EU (128-reg
// budget) is the proven-clean regime (R0/R3/R4/R5). (1024,4) = same budget.
__global__ __launch_bounds__(1024, 4) void lge_exp_kernel(
    const float* __restrict__ U_re, const float* __restrict__ U_im,
    const float* __restrict__ W_re, const float* __restrict__ W_im,
    const float* __restrict__ ahw,  float* __restrict__ out)
{
    const int gid   = blockIdx.x * 1024 + threadIdx.x;
    const int gsite = gid >> 2;        // 0..131071
    const int mu    = gid & 3;

    // ahw row for this mu: two aligned float4 loads
    const float4* ahw4 = (const float4*)ahw;
    float4 wlo = ahw4[mu * 2], whi = ahw4[mu * 2 + 1];
    const float wfv[8] = { wlo.x, wlo.y, wlo.z, wlo.w, whi.x, whi.y, whi.z, whi.w };

    const size_t sb = (size_t)gsite * 9;   // float offset within one feature plane

    // ---- E accumulation straight from global, feature-unrolled ----
    // E real part (antisymmetric, 3 DOF) needs only W_re elements 1,2,3,5,6,7
    // -> two dwordx3 per feature. E imag part needs all 9 of W_im.
    float er01 = 0.f, er02 = 0.f, er12 = 0.f;
    float a0=0.f,a1=0.f,a2=0.f,a3=0.f,a4=0.f,a5=0.f,a6=0.f,a7=0.f,a8=0.f;
    #pragma unroll
    for (int f = 0; f < 8; f++) {
        const float* pr = W_re + (size_t)f * (NSITES * 9) + sb;
        const float* pi = W_im + (size_t)f * (NSITES * 9) + sb;
        f3 q = ld3(pr + 1);            // w1 w2 w3
        f3 s = ld3(pr + 5);            // w5 w6 w7
        float wi[9];
        ld9(pi, wi);
        const float wf = wfv[f];
        er01 = fmaf(wf, q.x - q.z, er01);   // w1 - w3
        er02 = fmaf(wf, q.y - s.y, er02);   // w2 - w6
        er12 = fmaf(wf, s.x - s.z, er12);   // w5 - w7
        a0 = fmaf(wf, wi[0], a0); a1 = fmaf(wf, wi[1], a1); a2 = fmaf(wf, wi[2], a2);
        a3 = fmaf(wf, wi[3], a3); a4 = fmaf(wf, wi[4], a4); a5 = fmaf(wf, wi[5], a5);
        a6 = fmaf(wf, wi[6], a6); a7 = fmaf(wf, wi[7], a7); a8 = fmaf(wf, wi[8], a8);
    }

    // ---- U loads issued here: in flight under the whole Taylor/squaring chain
    const size_t ub = ((size_t)mu * NSITES + gsite) * 9;
    float ur[9], ui[9];
    ld9(U_re + ub, ur);
    ld9(U_im + ub, ui);

    const float ei01 = a1 + a3, ei02 = a2 + a6, ei12 = a5 + a7;
    const float t3  = (a0 + a4 + a8) * (2.f / 3.f);
    const float ed0 = fmaf(2.f, a0, -t3);
    const float ed1 = fmaf(2.f, a4, -t3);
    const float ed2 = fmaf(2.f, a8, -t3);       // == -ed0-ed1

    // ---- ||E||_F^2 ; p = tr(E^2)/2 = -r2/2 (REAL, free) ----
    float r2 = fmaf(er01, er01, fmaf(er02, er02, fmaf(er12, er12,
               fmaf(ei01, ei01, fmaf(ei02, ei02, ei12 * ei12)))));
    r2 = fmaf(2.f, r2, fmaf(ed0, ed0, fmaf(ed1, ed1, ed2 * ed2)));

    // ---- q = det(E) = -i*det(H), H = -iE hermitian -> q purely imaginary ----
    const float n01 = fmaf(ei01, ei01, er01 * er01);
    const float n02 = fmaf(ei02, ei02, er02 * er02);
    const float n12 = fmaf(ei12, ei12, er12 * er12);
    const float zre = fmaf(ei01, ei12, -(er01 * er12));   // Re(h01*h12)
    const float zim = -fmaf(ei01, er12, er01 * ei12);     // Im(h01*h12)
    const float detH = ed0 * ed1 * ed2
                     + 2.f * fmaf(zre, ei02, -(zim * er02))
                     - fmaf(ed0, n12, fmaf(ed1, n02, ed2 * n01));

    // ---- scaling: 2^sc >= 2*||E||_F >= 2*rho(E), from exponent bits of r2 ----
    int e; (void)frexpf(r2, &e);                 // r2 = m*2^e, m in [0.5,1)
    int sc = (e <= -2) ? 0 : min(1 + ((e + 1) >> 1), 40);
    const float inv  = __int_as_float((127 - sc) << 23);   // 2^-sc
    const float inv2 = inv * inv;
    const float px   = -0.5f * r2 * inv2;        // p of scaled X (real)
    const float qxi  = -detH * (inv2 * inv);     // q of scaled X = i*qxi

    // ---- Taylor of exp(X) in coefficient space (p real, q imaginary) ----
    cplx T0 = {1.f, 0.f}, T1 = {0.f, 0.f}, T2 = {0.f, 0.f};
    cplx S0 = {1.f, 0.f}, S1 = {0.f, 0.f}, S2 = {0.f, 0.f};
    #pragma unroll
    for (int n = 1; n <= 10; n++) {
        float c  = 1.f / (float)n;               // folds to a literal
        float qc = qxi * c;
        cplx nT0 = { -qc * T2.im, qc * T2.re };
        cplx nT1 = { c * fmaf(px, T2.re, T0.re), c * fmaf(px, T2.im, T0.im) };
        cplx nT2 = { c * T1.re, c * T1.im };
        T0 = nT0; T1 = nT1; T2 = nT2;
        S0 = cadd(S0, T0); S1 = cadd(S1, T1); S2 = cadd(S2, T2);
    }

    // ---- repeated squaring in coefficient space ----
    const float q2 = 2.f * qxi;
    for (int k = 0; k < sc; k++) {
        cplx f0 = S0, f1 = S1, f2 = S2;
        cplx f12 = cmul(f1, f2);
        cplx f01 = cmul(f0, f1);
        cplx f02 = cmul(f0, f2);
        float f00re = fmaf(f0.re, f0.re, -(f0.im * f0.im)), f00im = 2.f * f0.re * f0.im;
        float f11re = fmaf(f1.re, f1.re, -(f1.im * f1.im)), f11im = 2.f * f1.re * f1.im;
        float f22re = fmaf(f2.re, f2.re, -(f2.im * f2.im)), f22im = 2.f * f2.re * f2.im;
        S0.re = fmaf(-q2, f12.im, f00re);
        S0.im = fmaf( q2, f12.re, f00im);
        S1.re = fmaf(-qxi, f22im, 2.f * fmaf(px, f12.re, f01.re));
        S1.im = fmaf( qxi, f22re, 2.f * fmaf(px, f12.im, f01.im));
        S2.re = fmaf(px, f22re, fmaf(2.f, f02.re, f11re));
        S2.im = fmaf(px, f22im, fmaf(2.f, f02.im, f11im));
    }
    const cplx g0 = S0;
    const cplx g1 = { S1.re * inv,  S1.im * inv  };
    const cplx g2 = { S2.re * inv2, S2.im * inv2 };

    // ---- apply: out = Re[ g0 U + g1 (E U) + g2 (E (E U)) ], column-wise ----
    float o[9];
    #pragma unroll
    for (int b = 0; b < 3; b++) {
        cplx m0 = { ur[b],     ui[b]     };
        cplx m1 = { ur[3 + b], ui[3 + b] };
        cplx m2 = { ur[6 + b], ui[6 + b] };
        cplx v0, v1, v2, z0, z1, z2;
        ECOL(m0, m1, m2, v0, v1, v2);   // V col = E * U col
        ECOL(v0, v1, v2, z0, z1, z2);   // Z col = E * V col
        o[b]     = OCOMB(m0, v0, z0);
        o[3 + b] = OCOMB(m1, v1, z1);
        o[6 + b] = OCOMB(m2, v2, z2);
    }

    float* ob = out + ub;
    *(f3*)(ob)     = { o[0], o[1], o[2] };
    *(f3*)(ob + 3) = { o[3], o[4], o[5] };
    *(f3*)(ob + 6) = { o[6], o[7], o[8] };
}

extern "C" void kernel_launch(void* const* d_in, const int* in_sizes, int n_in,
                              void* d_out, int out_size, void* d_ws, size_t ws_size,
                              hipStream_t stream) {
    const float* U_re = (const float*)d_in[0];
    const float* U_im = (const float*)d_in[1];
    const float* W_re = (const float*)d_in[2];
    const float* W_im = (const float*)d_in[3];
    const float* ahw  = (const float*)d_in[4];
    float* out = (float*)d_out;
    // one lane per (site, mu): 524288 lanes = 512 blocks x 1024 threads.
    // Fewer, fatter workgroups: dispatch tail 2048 WGs -> 512 WGs (~-20 us).
    lge_exp_kernel<<<dim3(NSITES * 4 / 1024), dim3(1024), 0, stream>>>(
        U_re, U_im, W_re, W_im, ahw, out);
}